// Round 15
// baseline (306.728 us; speedup 1.0000x reference)
//
#include <hip/hip_runtime.h>
#include <hip/hip_bf16.h>

typedef __hip_bfloat16 bf16;
typedef short s16;
typedef __attribute__((ext_vector_type(4))) short s16x4;
typedef __attribute__((ext_vector_type(8))) short s16x8;
typedef __attribute__((ext_vector_type(4))) float f32x4;

__device__ __forceinline__ s16 f2b(float f){
    unsigned u = __float_as_uint(f);
    unsigned r = (u + 0x7FFFu + ((u >> 16) & 1u)) >> 16;
    return (s16)r;
}
__device__ __forceinline__ float b2f_bits(s16 v){
    return __uint_as_float(((unsigned)(unsigned short)v) << 16);
}

// ---------------------------------------------------------------------------
// A) fused prep: blocks 0..255 = x transpose (NCHW fp32 -> CL bf16-bits);
//    blocks 256..831 = conv-weight pack ([co][ci][3][3] -> [cc][tap][co][ci32])
// ---------------------------------------------------------------------------
__global__ __launch_bounds__(256) void prep_k(const float* __restrict__ x, s16* __restrict__ xcl,
                                              const float* __restrict__ w, s16* __restrict__ wpk){
    __shared__ s16 lb[64][258];
    int blk = blockIdx.x, t = threadIdx.x;
    if (blk < 256){
        int h = blk & 63, b = blk >> 6;
        for (int i = t; i < 16384; i += 256){
            int ci = i >> 6, ww = i & 63;
            lb[ww][ci] = f2b(x[((b*256 + ci)*64 + h)*64 + ww]);
        }
        __syncthreads();
        for (int i = t; i < 16384; i += 256){
            int ww = i >> 8, ci = i & 255;
            xcl[(b*4096 + h*64 + ww)*256 + ci] = lb[ww][ci];
        }
    } else {
        int base = (blk - 256)*1024 + t;
        #pragma unroll
        for (int k = 0; k < 4; ++k){
            int idx = base + k*256;              // < 589824
            int cil = idx & 31;
            int r   = idx >> 5;
            int co  = r & 255;
            int r2  = r >> 8;
            int tap = r2 % 9, cc = r2 / 9;
            wpk[idx] = f2b(w[(co*256 + cc*32 + cil)*9 + tap]);
        }
    }
}

// ---------------------------------------------------------------------------
// B) 3x3 conv 256->256, MFMA implicit GEMM v3:
//    - A-fragments loaded DIRECTLY from global xcl (16B/lane contiguous;
//      ~12 KB block working set -> L1-resident; no x-staging, no x barrier)
//    - only weights in LDS, restrided to 40 shorts (16B rows) so B-frags are
//      single ds_read_b128 (2-way bank alias = free)
//    - LDS 46 KB; barriers only around the 9-iter w-stage.
// ---------------------------------------------------------------------------
__global__ __launch_bounds__(256) void conv3x3m_k(const s16* __restrict__ xcl,
        const s16* __restrict__ wpk, const float* __restrict__ bias,
        bf16* __restrict__ y0){
    __shared__ alignas(16) s16 smem[23040];      // wls [9 tap][64 co][40] = 46 KB
    const int sp = blockIdx.x, cog = blockIdx.y;
    const int b = sp >> 5, h0 = (sp & 31)*2;
    const int t = threadIdx.x;
    const int wv = t >> 6, lane = t & 63;
    const int lm = lane & 15, g = lane >> 4;

    f32x4 acc[2][4];
    #pragma unroll
    for (int mi = 0; mi < 2; ++mi)
        #pragma unroll
        for (int ni = 0; ni < 4; ++ni) acc[mi][ni] = (f32x4){0.f,0.f,0.f,0.f};

    // per-lane spatial coords for the two m-tiles
    int hr0 = ((wv*2 + 0)*16 + lm) >> 6, ww0 = ((wv*2 + 0)*16 + lm) & 63;
    int hr1 = ((wv*2 + 1)*16 + lm) >> 6, ww1 = ((wv*2 + 1)*16 + lm) & 63;

    for (int cc = 0; cc < 8; ++cc){
        __syncthreads();
        for (int i = t; i < 2304; i += 256){
            int g8 = i & 3, co = (i>>2) & 63, tap = i >> 8;
            s16x8 v = *(const s16x8*)&wpk[((cc*9 + tap)*256 + cog*64 + co)*32 + g8*8];
            *(s16x8*)&smem[(tap*64 + co)*40 + g8*8] = v;
        }
        __syncthreads();
        #pragma unroll
        for (int tap = 0; tap < 9; ++tap){
            const int kh = tap/3, kw = tap%3;
            s16x8 bfr[4], afr[2];
            #pragma unroll
            for (int ni = 0; ni < 4; ++ni)
                bfr[ni] = *(const s16x8*)&smem[(tap*64 + ni*16 + lm)*40 + g*8];
            {
                int hh = h0 + hr0 + kh - 1, ww = ww0 + kw - 1;
                s16x8 v = {0,0,0,0,0,0,0,0};
                if ((unsigned)hh < 64u && (unsigned)ww < 64u)
                    v = *(const s16x8*)&xcl[(b*4096 + hh*64 + ww)*256 + cc*32 + g*8];
                afr[0] = v;
            }
            {
                int hh = h0 + hr1 + kh - 1, ww = ww1 + kw - 1;
                s16x8 v = {0,0,0,0,0,0,0,0};
                if ((unsigned)hh < 64u && (unsigned)ww < 64u)
                    v = *(const s16x8*)&xcl[(b*4096 + hh*64 + ww)*256 + cc*32 + g*8];
                afr[1] = v;
            }
            #pragma unroll
            for (int mi = 0; mi < 2; ++mi)
                #pragma unroll
                for (int ni = 0; ni < 4; ++ni)
                    acc[mi][ni] = __builtin_amdgcn_mfma_f32_16x16x32_bf16(
                        afr[mi], bfr[ni], acc[mi][ni], 0, 0, 0);
        }
    }
    // epilogue: acc -> LDS [co][132 pad] -> coalesced bf16 stores (+bias)
    __syncthreads();
    float* ot = (float*)smem;                    // [64 co][132 m-pad] = 33.8 KB
    #pragma unroll
    for (int mi = 0; mi < 2; ++mi)
        #pragma unroll
        for (int ni = 0; ni < 4; ++ni)
            #pragma unroll
            for (int r = 0; r < 4; ++r){
                int m  = (wv*2 + mi)*16 + g*4 + r;   // row=(lane>>4)*4+reg (verified)
                int co = ni*16 + lm;                 // col=lane&15 (verified)
                ot[co*132 + m] = acc[mi][ni][r];
            }
    __syncthreads();
    for (int i = t; i < 8192; i += 256){
        int co = i >> 7, m = i & 127;
        float v = ot[co*132 + m] + bias[cog*64 + co];
        y0[((b*256 + cog*64 + co)*64 + h0 + (m>>6))*64 + (m & 63)] = __float2bfloat16(v);
    }
}

// ---------------------------------------------------------------------------
// C) fused separable depthwise (7/11/21) + residual, sliding-window (R14)
// ---------------------------------------------------------------------------
template<int K>
__device__ __forceinline__ void sep_branch(const float (*__restrict__ pl)[65], float (*__restrict__ hp)[65],
                                           int c, int t,
                                           const float* __restrict__ wh, const float* __restrict__ bh,
                                           const float* __restrict__ wv, const float* __restrict__ bv,
                                           float* acc){
    constexpr int P = K/2;
    constexpr int W = 16 + 2*P;
    float wk[K];
    #pragma unroll
    for (int j = 0; j < K; ++j) wk[j] = wh[c*K + j];
    float bhv = bh[c];
    {
        int h = t >> 2, w0 = (t & 3)*16;
        float win[W];
        #pragma unroll
        for (int j = 0; j < W; ++j){
            int ww = w0 - P + j;
            win[j] = (ww >= 0 && ww < 64) ? pl[h][ww] : 0.f;
        }
        __syncthreads();                 // prev-branch hp reads complete
        #pragma unroll
        for (int i = 0; i < 16; ++i){
            float s = bhv;
            #pragma unroll
            for (int k = 0; k < K; ++k) s += win[i+k]*wk[k];
            hp[h][w0 + i] = s;
        }
    }
    float vk[K];
    #pragma unroll
    for (int j = 0; j < K; ++j) vk[j] = wv[c*K + j];
    float bvv = bv[c];
    __syncthreads();                     // hp writes visible
    {
        int w = t & 63, h0 = (t >> 6)*16;
        float win[W];
        #pragma unroll
        for (int j = 0; j < W; ++j){
            int hh = h0 - P + j;
            win[j] = (hh >= 0 && hh < 64) ? hp[hh][w] : 0.f;
        }
        #pragma unroll
        for (int i = 0; i < 16; ++i){
            float s = bvv;
            #pragma unroll
            for (int k = 0; k < K; ++k) s += win[i+k]*vk[k];
            acc[i] += s;
        }
    }
}

__global__ __launch_bounds__(256) void sepconv_k(const bf16* __restrict__ y0,
        const float* __restrict__ w01, const float* __restrict__ b01,
        const float* __restrict__ w02, const float* __restrict__ b02,
        const float* __restrict__ w11, const float* __restrict__ b11,
        const float* __restrict__ w12, const float* __restrict__ b12,
        const float* __restrict__ w21, const float* __restrict__ b21,
        const float* __restrict__ w22, const float* __restrict__ b22,
        bf16* __restrict__ out1){
    __shared__ float pl[64][65];
    __shared__ float hp[64][65];
    int bc = blockIdx.x;             // b*256 + c
    int c = bc & 255;
    int t = threadIdx.x;
    const bf16* src = y0 + bc*4096;
    for (int i = t; i < 4096; i += 256) pl[i>>6][i&63] = __bfloat162float(src[i]);
    __syncthreads();
    float acc[16];
    #pragma unroll
    for (int k = 0; k < 16; ++k) acc[k] = 0.f;
    sep_branch<7 >(pl, hp, c, t, w01, b01, w02, b02, acc);
    sep_branch<11>(pl, hp, c, t, w11, b11, w12, b12, acc);
    sep_branch<21>(pl, hp, c, t, w21, b21, w22, b22, acc);
    bf16* dst = out1 + bc*4096;
    {
        int w = t & 63, h0 = (t >> 6)*16;
        #pragma unroll
        for (int i = 0; i < 16; ++i)
            dst[(h0 + i)*64 + w] = __float2bfloat16(acc[i] + pl[h0 + i][w]);
    }
}

// ---------------------------------------------------------------------------
// E) 1x1 projection 256->32, 4-way ci-split -> tTb (bf16) + rn2 (R14)
// ---------------------------------------------------------------------------
__global__ __launch_bounds__(256) void proj_k(const bf16* __restrict__ out1, const float* __restrict__ wp,
                                              const float* __restrict__ bp,
                                              s16* __restrict__ tTb, float* __restrict__ rn2){
    __shared__ float wl[256*32];         // [ci][cc] fp32, 32 KB
    __shared__ s16 part[4][64][36];      // bf16 partials, 18.4 KB
    int pt = blockIdx.x, b = blockIdx.y, t = threadIdx.x;
    int q = t >> 6, lane = t & 63;
    for (int i = t; i < 8192; i += 256){
        int ci = i >> 5, cc = i & 31;
        wl[ci*32 + cc] = wp[cc*256 + ci];
    }
    __syncthreads();
    int p = pt*64 + lane;
    float acc[32] = {};
    const bf16* xb = out1 + b*1048576 + p;
    for (int ci = q*64; ci < q*64 + 64; ++ci){
        float v = __bfloat162float(xb[ci*4096]);
        const float* wr = &wl[ci*32];
        #pragma unroll
        for (int c8 = 0; c8 < 8; ++c8){
            float4 w4 = *(const float4*)&wr[c8*4];
            acc[c8*4+0] += w4.x*v; acc[c8*4+1] += w4.y*v;
            acc[c8*4+2] += w4.z*v; acc[c8*4+3] += w4.w*v;
        }
    }
    #pragma unroll
    for (int cc = 0; cc < 32; ++cc) part[q][lane][cc] = f2b(acc[cc]);
    __syncthreads();
    int p_loc = t >> 2, qq = t & 3;
    int pg = pt*64 + p_loc;
    float a8[8];
    float ss = 0.f;
    #pragma unroll
    for (int c = 0; c < 8; ++c){
        int cc = qq*8 + c;
        float v = b2f_bits(part[0][p_loc][cc]) + b2f_bits(part[1][p_loc][cc])
                + b2f_bits(part[2][p_loc][cc]) + b2f_bits(part[3][p_loc][cc]) + bp[cc];
        a8[c] = v;
        ss += v*v;
    }
    ss += __shfl_xor(ss, 1, 4);
    ss += __shfl_xor(ss, 2, 4);
    if (qq == 0) rn2[b*4096 + pg] = 1.f / fmaxf(sqrtf(ss), 1e-12f);
    s16x8 o8;
    #pragma unroll
    for (int c = 0; c < 8; ++c) o8[c] = f2b(a8[c]);
    *(s16x8*)&tTb[(b*4096 + pg)*32 + qq*8] = o8;
}

// ---------------------------------------------------------------------------
// G1) Gram via MFMA, staged from tTb (R14)
// ---------------------------------------------------------------------------
__global__ __launch_bounds__(256) void gramm_k(const s16* __restrict__ tTb, float* __restrict__ part){
    __shared__ alignas(16) s16 ts[32*268];       // 16.75 KB
    int ks = blockIdx.x, b = blockIdx.y, t = threadIdx.x;
    {
        const s16* src = &tTb[(b*4096 + ks*256 + t)*32];
        s16 row[32];
        #pragma unroll
        for (int q = 0; q < 4; ++q){
            s16x8 v = *(const s16x8*)&src[q*8];
            #pragma unroll
            for (int e = 0; e < 8; ++e) row[q*8 + e] = v[e];
        }
        #pragma unroll
        for (int cc = 0; cc < 32; ++cc) ts[cc*268 + t] = row[cc];
    }
    __syncthreads();
    int wv = t >> 6, lane = t & 63, lm = lane & 15, g = lane >> 4;
    int mi = wv >> 1, ni = wv & 1;
    f32x4 acc = (f32x4){0.f,0.f,0.f,0.f};
    const s16* ar = &ts[(mi*16 + lm)*268];
    const s16* br = &ts[(ni*16 + lm)*268];
    #pragma unroll
    for (int kk = 0; kk < 8; ++kk){
        const s16* ap = ar + kk*32 + g*8;
        s16x4 alo = *(const s16x4*)ap;
        s16x4 ahi = *(const s16x4*)(ap + 4);
        s16x8 af = __builtin_shufflevector(alo, ahi, 0,1,2,3,4,5,6,7);
        const s16* bp = br + kk*32 + g*8;
        s16x4 blo = *(const s16x4*)bp;
        s16x4 bhi = *(const s16x4*)(bp + 4);
        s16x8 bf = __builtin_shufflevector(blo, bhi, 0,1,2,3,4,5,6,7);
        acc = __builtin_amdgcn_mfma_f32_16x16x32_bf16(af, bf, acc, 0, 0, 0);
    }
    float* pd = part + (b*16 + ks)*1024;
    #pragma unroll
    for (int r = 0; r < 4; ++r){
        int i = mi*16 + g*4 + r, j = ni*16 + lm;
        pd[i*32 + j] = acc[r];
    }
}

// ---------------------------------------------------------------------------
// G2+G3) fused: attn1 softmax (rn1 from gram diag) + fold into WtT/WoT/bfo
// ---------------------------------------------------------------------------
__global__ __launch_bounds__(256) void afold_k(const float* __restrict__ part,
        const float* __restrict__ w3, const float* __restrict__ b3,
        const float* __restrict__ w4, const float* __restrict__ b4,
        float* __restrict__ WtT, float* __restrict__ WoT, float* __restrict__ bfo){
    __shared__ float rn[32];
    __shared__ float rsum[32];
    __shared__ float a1[1024];     // attn1[i][j] (exp, then normalized)
    __shared__ float w3a[1024];    // [cc][j]
    __shared__ float w3bs[1024];   // [cc][j]
    int b = blockIdx.x, t = threadIdx.x;
    if (t < 32){
        float gjj = 0.f;
        #pragma unroll 8
        for (int ps = 0; ps < 16; ++ps) gjj += part[(b*16+ps)*1024 + t*33];
        rn[t] = 1.f / fmaxf(sqrtf(gjj), 1e-12f);
    }
    for (int idx = t; idx < 1024; idx += 256){
        int i = idx >> 5, j = idx & 31;
        w3bs[idx] = w3[i*64 + 32 + j];
    }
    __syncthreads();
    for (int e = t; e < 1024; e += 256){
        int i = e >> 5, j = e & 31;
        float gij = 0.f;
        #pragma unroll 8
        for (int ps = 0; ps < 16; ++ps) gij += part[(b*16+ps)*1024 + e];
        a1[e] = __expf(rn[i]*rn[j]*gij);
    }
    __syncthreads();
    if (t < 32){
        float s = 0.f;
        #pragma unroll 8
        for (int j = 0; j < 32; ++j) s += a1[t*32 + j];
        rsum[t] = 1.f / s;
    }
    __syncthreads();
    for (int e = t; e < 1024; e += 256) a1[e] *= rsum[e >> 5];
    __syncthreads();
    for (int idx = t; idx < 1024; idx += 256){
        int cc = idx >> 5, j = idx & 31;
        float s = 0.f;
        #pragma unroll 8
        for (int i = 0; i < 32; ++i) s += w3[cc*64 + i]*a1[i*32 + j];
        w3a[idx] = s;
    }
    __syncthreads();
    int co = t;
    float w4r[32];
    #pragma unroll
    for (int cc = 0; cc < 32; ++cc) w4r[cc] = w4[co*32 + cc];
    float bfv = b4[co];
    #pragma unroll
    for (int cc = 0; cc < 32; ++cc) bfv += w4r[cc]*b3[cc];
    bfo[b*256 + co] = bfv;
    for (int j = 0; j < 32; ++j){
        float st = w4r[j];           // w4 identity term = +t residual through w4
        float so = 0.f;
        #pragma unroll 8
        for (int cc = 0; cc < 32; ++cc){
            st += w4r[cc]*w3a[cc*32 + j];
            so += w4r[cc]*w3bs[cc*32 + j];
        }
        WtT[(b*32 + j)*256 + co] = st;
        WoT[(b*32 + j)*256 + co] = so;
    }
}

// ---------------------------------------------------------------------------
// J) spatial attention via MFMA flash — 4-way j-chunk split (R14)
// ---------------------------------------------------------------------------
__global__ __launch_bounds__(256) void flashm_k(const s16* __restrict__ tTb, const float* __restrict__ rn2,
                                                float* __restrict__ partA, float* __restrict__ partL){
    __shared__ alignas(16) s16 kvb[128*36];      // [j][ci]   9216 B
    __shared__ alignas(16) s16 vts[32*132];      // [ci][j]   8448 B
    __shared__ alignas(16) s16 pls[4][16*132];   // per-wave P [m][j] 16896 B
    __shared__ float rnj[128];
    __shared__ float ri[64];
    const int ib = blockIdx.x, b = blockIdx.y, chunk = blockIdx.z;
    const int t = threadIdx.x, wv = t >> 6, lane = t & 63;
    const int lm = lane & 15, g = lane >> 4;
    const int i0 = ib*64;

    if (t < 64) ri[t] = rn2[b*4096 + i0 + t];
    s16x8 qf = *(const s16x8*)&tTb[(b*4096 + i0 + wv*16 + lm)*32 + g*8];
    __syncthreads();
    float rni4[4];
    #pragma unroll
    for (int r = 0; r < 4; ++r) rni4[r] = ri[wv*16 + g*4 + r];

    f32x4 oacc[2];
    oacc[0] = (f32x4){0.f,0.f,0.f,0.f};
    oacc[1] = (f32x4){0.f,0.f,0.f,0.f};
    float lacc[4] = {0.f,0.f,0.f,0.f};
    s16* pw = pls[wv];

    for (int jt = chunk*8; jt < chunk*8 + 8; ++jt){
        const int j0 = jt*128;
        __syncthreads();
        for (int gi = t; gi < 512; gi += 256){
            int j = gi >> 2, g8 = gi & 3;
            s16x8 v = *(const s16x8*)&tTb[(b*4096 + j0 + j)*32 + g8*8];
            s16* d = &kvb[j*36 + g8*8];
            *(s16x4*)d       = __builtin_shufflevector(v, v, 0,1,2,3);
            *(s16x4*)(d + 4) = __builtin_shufflevector(v, v, 4,5,6,7);
            #pragma unroll
            for (int e = 0; e < 8; ++e) vts[(g8*8 + e)*132 + j] = v[e];
        }
        if (t < 128) rnj[t] = rn2[b*4096 + j0 + t];
        __syncthreads();
        #pragma unroll
        for (int nt = 0; nt < 8; ++nt){
            const s16* bp = &kvb[(nt*16 + lm)*36 + g*8];
            s16x4 blo = *(const s16x4*)bp;
            s16x4 bhi = *(const s16x4*)(bp + 4);
            s16x8 bf = __builtin_shufflevector(blo, bhi, 0,1,2,3,4,5,6,7);
            f32x4 s = __builtin_amdgcn_mfma_f32_16x16x32_bf16(qf, bf,
                        (f32x4){0.f,0.f,0.f,0.f}, 0, 0, 0);
            float rj = rnj[nt*16 + lm];
            #pragma unroll
            for (int r = 0; r < 4; ++r){
                float e = __expf(s[r]*rni4[r]*rj);
                lacc[r] += e;
                pw[(g*4 + r)*132 + nt*16 + lm] = f2b(e);
            }
        }
        #pragma unroll
        for (int ks = 0; ks < 4; ++ks){
            const s16* ap = &pw[lm*132 + ks*32 + g*8];
            s16x4 alo = *(const s16x4*)ap;
            s16x4 ahi = *(const s16x4*)(ap + 4);
            s16x8 af = __builtin_shufflevector(alo, ahi, 0,1,2,3,4,5,6,7);
            #pragma unroll
            for (int n2 = 0; n2 < 2; ++n2){
                const s16* vp = &vts[(n2*16 + lm)*132 + ks*32 + g*8];
                s16x4 vlo = *(const s16x4*)vp;
                s16x4 vhi = *(const s16x4*)(vp + 4);
                s16x8 vf = __builtin_shufflevector(vlo, vhi, 0,1,2,3,4,5,6,7);
                oacc[n2] = __builtin_amdgcn_mfma_f32_16x16x32_bf16(af, vf, oacc[n2], 0, 0, 0);
            }
        }
    }
    #pragma unroll
    for (int r = 0; r < 4; ++r){
        float v = lacc[r];
        v += __shfl_xor(v, 1, 16); v += __shfl_xor(v, 2, 16);
        v += __shfl_xor(v, 4, 16); v += __shfl_xor(v, 8, 16);
        lacc[r] = v;
    }
    const int base = (b*4 + chunk)*4096 + i0 + wv*16;
    #pragma unroll
    for (int n2 = 0; n2 < 2; ++n2)
        #pragma unroll
        for (int r = 0; r < 4; ++r)
            partA[(base + g*4 + r)*32 + n2*16 + lm] = oacc[n2][r];
    if (lm == 0){
        #pragma unroll
        for (int r = 0; r < 4; ++r) partL[base + g*4 + r] = lacc[r];
    }
}

// ---------------------------------------------------------------------------
// L) fused epilogue — t from tTb, 4-chunk merge (R14)
// ---------------------------------------------------------------------------
__global__ __launch_bounds__(256) void finalfuse_k(const s16* __restrict__ tTb,
        const float* __restrict__ partA, const float* __restrict__ partL,
        const float* __restrict__ WtT, const float* __restrict__ WoT,
        const float* __restrict__ bfo, float* __restrict__ out){
    int pt = blockIdx.x, cog = blockIdx.y, b = blockIdx.z, t = threadIdx.x;
    int p = pt*256 + t;
    float l = 0.f;
    #pragma unroll
    for (int c = 0; c < 4; ++c) l += partL[(b*4 + c)*4096 + p];
    float inv = 1.f / l;
    float v3[32];
    #pragma unroll
    for (int q = 0; q < 8; ++q){
        float4 s0 = *(const float4*)&partA[((b*4 + 0)*4096 + p)*32 + q*4];
        float4 s1 = *(const float4*)&partA[((b*4 + 1)*4096 + p)*32 + q*4];
        float4 s2 = *(const float4*)&partA[((b*4 + 2)*4096 + p)*32 + q*4];
        float4 s3 = *(const float4*)&partA[((b*4 + 3)*4096 + p)*32 + q*4];
        v3[q*4+0] = (s0.x + s1.x + s2.x + s3.x)*inv;
        v3[q*4+1] = (s0.y + s1.y + s2.y + s3.y)*inv;
        v3[q*4+2] = (s0.z + s1.z + s2.z + s3.z)*inv;
        v3[q*4+3] = (s0.w + s1.w + s2.w + s3.w)*inv;
    }
    float vt[32];
    {
        const s16* tp = &tTb[(b*4096 + p)*32];
        #pragma unroll
        for (int q = 0; q < 4; ++q){
            s16x8 v = *(const s16x8*)&tp[q*8];
            #pragma unroll
            for (int e = 0; e < 8; ++e) vt[q*8 + e] = b2f_bits(v[e]);
        }
    }
    float acc[32];
    #pragma unroll
    for (int co = 0; co < 32; ++co) acc[co] = bfo[b*256 + cog*32 + co];
    for (int j = 0; j < 32; ++j){
        float vtj = vt[j];
        float vo  = v3[j];
        const float* wtr = WtT + (b*32 + j)*256 + cog*32;   // wave-uniform
        const float* wor = WoT + (b*32 + j)*256 + cog*32;   // wave-uniform
        #pragma unroll
        for (int co = 0; co < 32; ++co) acc[co] += wtr[co]*vtj + wor[co]*vo;
    }
    #pragma unroll
    for (int co = 0; co < 32; ++co)
        out[((b*256 + cog*32 + co)*4096) + p] = acc[co];
}

// ---------------------------------------------------------------------------
// Workspace layout (bytes), peak ~19.0 MB:
//   [0,        8388608)  xcl -> out1 -> gram part (256 KB) -> flash partA (8 MB)
//   [8388608, 16777216)  y0  -> tTb (1 MB at +10.5 MB)
//   [12582912, ...)      WtT/WoT/bfo (260 KB)
//   [16777216, ...)      wpk -> partL (256 KB);  rn2 near byte 18.9 MB
// ---------------------------------------------------------------------------
extern "C" void kernel_launch(void* const* d_in, const int* in_sizes, int n_in,
                              void* d_out, int out_size, void* d_ws, size_t ws_size,
                              hipStream_t stream) {
    const float* x      = (const float*)d_in[0];
    const float* w_conv = (const float*)d_in[1];
    const float* b_conv = (const float*)d_in[2];
    const float* w01 = (const float*)d_in[3];  const float* b01 = (const float*)d_in[4];
    const float* w02 = (const float*)d_in[5];  const float* b02 = (const float*)d_in[6];
    const float* w11 = (const float*)d_in[7];  const float* b11 = (const float*)d_in[8];
    const float* w12 = (const float*)d_in[9];  const float* b12 = (const float*)d_in[10];
    const float* w21 = (const float*)d_in[11]; const float* b21 = (const float*)d_in[12];
    const float* w22 = (const float*)d_in[13]; const float* b22 = (const float*)d_in[14];
    const float* w_proj = (const float*)d_in[15]; const float* b_proj = (const float*)d_in[16];
    const float* w3 = (const float*)d_in[17]; const float* b3 = (const float*)d_in[18];
    const float* w4 = (const float*)d_in[19]; const float* b4 = (const float*)d_in[20];

    char* wsb = (char*)d_ws;
    s16*   xcl  = (s16*)wsb;                        // 4,194,304 s16 (conv input)
    bf16*  out1 = (bf16*)wsb;                       // same slot, after conv
    bf16*  y0   = (bf16*)(wsb + 8388608);           // 4,194,304 bf16
    s16*   wpk  = (s16*)(wsb + 16777216);           // 589,824 s16
    float* f    = (float*)d_ws;
    float* part   = f + 0;         // gram partials 4x16x1024 f (out1 dead)
    float* partA  = f + 0;         // flash partials 4x4x4096x32 f = 8 MB
    s16*   tTb    = (s16*)(wsb + 10485760);         // 524,288 s16 = 1 MB
    float* WtT    = f + 3145728;   // byte 12,582,912  (4x32x256 f)
    float* WoT    = f + 3178496;
    float* bfo    = f + 3211264;
    float* partL  = f + 4194304;   // byte 16,777,216 (wpk dead by flashm), 64K f
    float* rn2    = f + 4726912;

    prep_k<<<dim3(832), 256, 0, stream>>>(x, xcl, w_conv, wpk);
    conv3x3m_k<<<dim3(128, 4), 256, 0, stream>>>(xcl, wpk, b_conv, y0);
    sepconv_k<<<dim3(1024), 256, 0, stream>>>(y0, w01, b01, w02, b02,
                                              w11, b11, w12, b12,
                                              w21, b21, w22, b22, out1);
    proj_k<<<dim3(64, 4), 256, 0, stream>>>(out1, w_proj, b_proj, tTb, rn2);
    gramm_k<<<dim3(16, 4), 256, 0, stream>>>(tTb, part);
    afold_k<<<dim3(4), 256, 0, stream>>>(part, w3, b3, w4, b4, WtT, WoT, bfo);
    flashm_k<<<dim3(64, 4, 4), 256, 0, stream>>>(tTb, rn2, partA, partL);
    finalfuse_k<<<dim3(16, 8, 4), 256, 0, stream>>>(tTb, partA, partL, WtT, WoT, bfo,
                                                    (float*)d_out);
}

// Round 16
// 297.113 us; speedup vs baseline: 1.0324x; 1.0324x over previous
//
#include <hip/hip_runtime.h>
#include <hip/hip_bf16.h>

typedef __hip_bfloat16 bf16;
typedef short s16;
typedef __attribute__((ext_vector_type(4))) short s16x4;
typedef __attribute__((ext_vector_type(8))) short s16x8;
typedef __attribute__((ext_vector_type(4))) float f32x4;

__device__ __forceinline__ s16 f2b(float f){
    unsigned u = __float_as_uint(f);
    unsigned r = (u + 0x7FFFu + ((u >> 16) & 1u)) >> 16;
    return (s16)r;
}
__device__ __forceinline__ float b2f_bits(s16 v){
    return __uint_as_float(((unsigned)(unsigned short)v) << 16);
}

// ---------------------------------------------------------------------------
// A) fused prep: blocks 0..255 = x transpose (NCHW fp32 -> CL bf16-bits);
//    blocks 256..831 = conv-weight pack ([co][ci][3][3] -> [cc][tap][co][ci32])
// ---------------------------------------------------------------------------
__global__ __launch_bounds__(256) void prep_k(const float* __restrict__ x, s16* __restrict__ xcl,
                                              const float* __restrict__ w, s16* __restrict__ wpk){
    __shared__ s16 lb[64][258];
    int blk = blockIdx.x, t = threadIdx.x;
    if (blk < 256){
        int h = blk & 63, b = blk >> 6;
        for (int i = t; i < 16384; i += 256){
            int ci = i >> 6, ww = i & 63;
            lb[ww][ci] = f2b(x[((b*256 + ci)*64 + h)*64 + ww]);
        }
        __syncthreads();
        for (int i = t; i < 16384; i += 256){
            int ww = i >> 8, ci = i & 255;
            xcl[(b*4096 + h*64 + ww)*256 + ci] = lb[ww][ci];
        }
    } else {
        int base = (blk - 256)*1024 + t;
        #pragma unroll
        for (int k = 0; k < 4; ++k){
            int idx = base + k*256;              // < 589824
            int cil = idx & 31;
            int r   = idx >> 5;
            int co  = r & 255;
            int r2  = r >> 8;
            int tap = r2 % 9, cc = r2 / 9;
            wpk[idx] = f2b(w[(co*256 + cc*32 + cil)*9 + tap]);
        }
    }
}

// ---------------------------------------------------------------------------
// B) 3x3 conv 256->256 as MFMA implicit GEMM — R14 version (proven 51 us).
//    M=128 (2 h-rows x 64 w) x N=64 co; x + w staged in LDS (60.5 KB).
// ---------------------------------------------------------------------------
__global__ __launch_bounds__(256) void conv3x3m_k(const s16* __restrict__ xcl,
        const s16* __restrict__ wpk, const float* __restrict__ bias,
        bf16* __restrict__ y0){
    __shared__ alignas(16) s16 smem[30240];      // 60.5 KB
    s16* xls = smem;                             // [4 rows][66 w][36 ci-pad]
    s16* wls = smem + 9504;                      // [9 tap][64 co][36 ci-pad]
    const int sp = blockIdx.x, cog = blockIdx.y;
    const int b = sp >> 5, h0 = (sp & 31)*2;
    const int t = threadIdx.x;
    const int wv = t >> 6, lane = t & 63;
    const int lm = lane & 15, g = lane >> 4;

    f32x4 acc[2][4];
    #pragma unroll
    for (int mi = 0; mi < 2; ++mi)
        #pragma unroll
        for (int ni = 0; ni < 4; ++ni) acc[mi][ni] = (f32x4){0.f,0.f,0.f,0.f};

    for (int cc = 0; cc < 8; ++cc){
        __syncthreads();
        for (int i = t; i < 1056; i += 256){
            int g8 = i & 3, wi = (i>>2) % 66, r = (i>>2) / 66;
            int h = h0 - 1 + r, w = wi - 1;
            s16x8 v = {0,0,0,0,0,0,0,0};
            if (h >= 0 && h < 64 && w >= 0 && w < 64)
                v = *(const s16x8*)&xcl[(b*4096 + h*64 + w)*256 + cc*32 + g8*8];
            s16* d = &xls[(r*66 + wi)*36 + g8*8];
            *(s16x4*)d       = __builtin_shufflevector(v, v, 0,1,2,3);
            *(s16x4*)(d + 4) = __builtin_shufflevector(v, v, 4,5,6,7);
        }
        for (int i = t; i < 2304; i += 256){
            int g8 = i & 3, co = (i>>2) & 63, tap = i >> 8;
            s16x8 v = *(const s16x8*)&wpk[((cc*9 + tap)*256 + cog*64 + co)*32 + g8*8];
            s16* d = &wls[(tap*64 + co)*36 + g8*8];
            *(s16x4*)d       = __builtin_shufflevector(v, v, 0,1,2,3);
            *(s16x4*)(d + 4) = __builtin_shufflevector(v, v, 4,5,6,7);
        }
        __syncthreads();
        #pragma unroll
        for (int tap = 0; tap < 9; ++tap){
            const int kh = tap/3, kw = tap%3;
            s16x8 bfr[4], afr[2];
            #pragma unroll
            for (int ni = 0; ni < 4; ++ni){
                const s16* p = &wls[(tap*64 + ni*16 + lm)*36 + g*8];
                s16x4 lo = *(const s16x4*)p;
                s16x4 hi = *(const s16x4*)(p + 4);
                bfr[ni] = __builtin_shufflevector(lo, hi, 0,1,2,3,4,5,6,7);
            }
            #pragma unroll
            for (int mi = 0; mi < 2; ++mi){
                int m = (wv*2 + mi)*16 + lm;
                int hr = m >> 6, ww = m & 63;
                const s16* p = &xls[((hr + kh)*66 + (ww + kw))*36 + g*8];
                s16x4 lo = *(const s16x4*)p;
                s16x4 hi = *(const s16x4*)(p + 4);
                afr[mi] = __builtin_shufflevector(lo, hi, 0,1,2,3,4,5,6,7);
            }
            #pragma unroll
            for (int mi = 0; mi < 2; ++mi)
                #pragma unroll
                for (int ni = 0; ni < 4; ++ni)
                    acc[mi][ni] = __builtin_amdgcn_mfma_f32_16x16x32_bf16(
                        afr[mi], bfr[ni], acc[mi][ni], 0, 0, 0);
        }
    }
    __syncthreads();
    float* ot = (float*)smem;                    // [64 co][132 m-pad]
    #pragma unroll
    for (int mi = 0; mi < 2; ++mi)
        #pragma unroll
        for (int ni = 0; ni < 4; ++ni)
            #pragma unroll
            for (int r = 0; r < 4; ++r){
                int m  = (wv*2 + mi)*16 + g*4 + r;
                int co = ni*16 + lm;
                ot[co*132 + m] = acc[mi][ni][r];
            }
    __syncthreads();
    for (int i = t; i < 8192; i += 256){
        int co = i >> 7, m = i & 127;
        float v = ot[co*132 + m] + bias[cog*64 + co];
        y0[((b*256 + cog*64 + co)*64 + h0 + (m>>6))*64 + (m & 63)] = __float2bfloat16(v);
    }
}

// ---------------------------------------------------------------------------
// C) fused separable depthwise (7/11/21) + residual, sliding-window, with
//    VECTORIZED global I/O: in = 2x s16x8 loads (16 B/lane), out = acc
//    transposed through hp (residual folded) then 2x s16x8 stores.
//    All new LDS patterns <= 2-way (free).
// ---------------------------------------------------------------------------
template<int K>
__device__ __forceinline__ void sep_branch(const float (*__restrict__ pl)[65], float (*__restrict__ hp)[65],
                                           int c, int t,
                                           const float* __restrict__ wh, const float* __restrict__ bh,
                                           const float* __restrict__ wv, const float* __restrict__ bv,
                                           float* acc){
    constexpr int P = K/2;
    constexpr int W = 16 + 2*P;
    float wk[K];
    #pragma unroll
    for (int j = 0; j < K; ++j) wk[j] = wh[c*K + j];
    float bhv = bh[c];
    {
        int h = t >> 2, w0 = (t & 3)*16;
        float win[W];
        #pragma unroll
        for (int j = 0; j < W; ++j){
            int ww = w0 - P + j;
            win[j] = (ww >= 0 && ww < 64) ? pl[h][ww] : 0.f;
        }
        __syncthreads();                 // prev-branch hp reads complete
        #pragma unroll
        for (int i = 0; i < 16; ++i){
            float s = bhv;
            #pragma unroll
            for (int k = 0; k < K; ++k) s += win[i+k]*wk[k];
            hp[h][w0 + i] = s;
        }
    }
    float vk[K];
    #pragma unroll
    for (int j = 0; j < K; ++j) vk[j] = wv[c*K + j];
    float bvv = bv[c];
    __syncthreads();                     // hp writes visible
    {
        int w = t & 63, h0 = (t >> 6)*16;
        float win[W];
        #pragma unroll
        for (int j = 0; j < W; ++j){
            int hh = h0 - P + j;
            win[j] = (hh >= 0 && hh < 64) ? hp[hh][w] : 0.f;
        }
        #pragma unroll
        for (int i = 0; i < 16; ++i){
            float s = bvv;
            #pragma unroll
            for (int k = 0; k < K; ++k) s += win[i+k]*vk[k];
            acc[i] += s;
        }
    }
}

__global__ __launch_bounds__(256) void sepconv_k(const bf16* __restrict__ y0,
        const float* __restrict__ w01, const float* __restrict__ b01,
        const float* __restrict__ w02, const float* __restrict__ b02,
        const float* __restrict__ w11, const float* __restrict__ b11,
        const float* __restrict__ w12, const float* __restrict__ b12,
        const float* __restrict__ w21, const float* __restrict__ b21,
        const float* __restrict__ w22, const float* __restrict__ b22,
        bf16* __restrict__ out1){
    __shared__ float pl[64][65];
    __shared__ float hp[64][65];
    int bc = blockIdx.x;             // b*256 + c
    int c = bc & 255;
    int t = threadIdx.x;
    const s16* src = (const s16*)(y0 + bc*4096);
    #pragma unroll
    for (int k = 0; k < 2; ++k){
        int chunk = t + k*256;                   // 0..511
        int h = chunk >> 3, w8 = (chunk & 7)*8;
        s16x8 v = *(const s16x8*)&src[h*64 + w8];
        #pragma unroll
        for (int e = 0; e < 8; ++e) pl[h][w8 + e] = b2f_bits(v[e]);
    }
    __syncthreads();
    float acc[16];
    #pragma unroll
    for (int k = 0; k < 16; ++k) acc[k] = 0.f;
    sep_branch<7 >(pl, hp, c, t, w01, b01, w02, b02, acc);
    sep_branch<11>(pl, hp, c, t, w11, b11, w12, b12, acc);
    sep_branch<21>(pl, hp, c, t, w21, b21, w22, b22, acc);
    // transpose epilogue: final values (incl. residual) into hp, then
    // vectorized bf16 stores (16 B/lane).
    __syncthreads();                 // all branch-21 hp reads done
    {
        int w = t & 63, h0 = (t >> 6)*16;
        #pragma unroll
        for (int i = 0; i < 16; ++i) hp[h0 + i][w] = acc[i] + pl[h0 + i][w];
    }
    __syncthreads();
    s16* dst = (s16*)(out1 + bc*4096);
    #pragma unroll
    for (int k = 0; k < 2; ++k){
        int chunk = t + k*256;
        int h = chunk >> 3, w8 = (chunk & 7)*8;
        s16x8 o;
        #pragma unroll
        for (int e = 0; e < 8; ++e) o[e] = f2b(hp[h][w8 + e]);
        *(s16x8*)&dst[h*64 + w8] = o;
    }
}

// ---------------------------------------------------------------------------
// E) 1x1 projection 256->32, 4-way ci-split -> tTb (bf16) + rn2 (R14)
// ---------------------------------------------------------------------------
__global__ __launch_bounds__(256) void proj_k(const bf16* __restrict__ out1, const float* __restrict__ wp,
                                              const float* __restrict__ bp,
                                              s16* __restrict__ tTb, float* __restrict__ rn2){
    __shared__ float wl[256*32];         // [ci][cc] fp32, 32 KB
    __shared__ s16 part[4][64][36];      // bf16 partials, 18.4 KB
    int pt = blockIdx.x, b = blockIdx.y, t = threadIdx.x;
    int q = t >> 6, lane = t & 63;
    for (int i = t; i < 8192; i += 256){
        int ci = i >> 5, cc = i & 31;
        wl[ci*32 + cc] = wp[cc*256 + ci];
    }
    __syncthreads();
    int p = pt*64 + lane;
    float acc[32] = {};
    const bf16* xb = out1 + b*1048576 + p;
    for (int ci = q*64; ci < q*64 + 64; ++ci){
        float v = __bfloat162float(xb[ci*4096]);
        const float* wr = &wl[ci*32];
        #pragma unroll
        for (int c8 = 0; c8 < 8; ++c8){
            float4 w4 = *(const float4*)&wr[c8*4];
            acc[c8*4+0] += w4.x*v; acc[c8*4+1] += w4.y*v;
            acc[c8*4+2] += w4.z*v; acc[c8*4+3] += w4.w*v;
        }
    }
    #pragma unroll
    for (int cc = 0; cc < 32; ++cc) part[q][lane][cc] = f2b(acc[cc]);
    __syncthreads();
    int p_loc = t >> 2, qq = t & 3;
    int pg = pt*64 + p_loc;
    float a8[8];
    float ss = 0.f;
    #pragma unroll
    for (int c = 0; c < 8; ++c){
        int cc = qq*8 + c;
        float v = b2f_bits(part[0][p_loc][cc]) + b2f_bits(part[1][p_loc][cc])
                + b2f_bits(part[2][p_loc][cc]) + b2f_bits(part[3][p_loc][cc]) + bp[cc];
        a8[c] = v;
        ss += v*v;
    }
    ss += __shfl_xor(ss, 1, 4);
    ss += __shfl_xor(ss, 2, 4);
    if (qq == 0) rn2[b*4096 + pg] = 1.f / fmaxf(sqrtf(ss), 1e-12f);
    s16x8 o8;
    #pragma unroll
    for (int c = 0; c < 8; ++c) o8[c] = f2b(a8[c]);
    *(s16x8*)&tTb[(b*4096 + pg)*32 + qq*8] = o8;
}

// ---------------------------------------------------------------------------
// G1) Gram via MFMA, staged from tTb (R14)
// ---------------------------------------------------------------------------
__global__ __launch_bounds__(256) void gramm_k(const s16* __restrict__ tTb, float* __restrict__ part){
    __shared__ alignas(16) s16 ts[32*268];       // 16.75 KB
    int ks = blockIdx.x, b = blockIdx.y, t = threadIdx.x;
    {
        const s16* src = &tTb[(b*4096 + ks*256 + t)*32];
        s16 row[32];
        #pragma unroll
        for (int q = 0; q < 4; ++q){
            s16x8 v = *(const s16x8*)&src[q*8];
            #pragma unroll
            for (int e = 0; e < 8; ++e) row[q*8 + e] = v[e];
        }
        #pragma unroll
        for (int cc = 0; cc < 32; ++cc) ts[cc*268 + t] = row[cc];
    }
    __syncthreads();
    int wv = t >> 6, lane = t & 63, lm = lane & 15, g = lane >> 4;
    int mi = wv >> 1, ni = wv & 1;
    f32x4 acc = (f32x4){0.f,0.f,0.f,0.f};
    const s16* ar = &ts[(mi*16 + lm)*268];
    const s16* br = &ts[(ni*16 + lm)*268];
    #pragma unroll
    for (int kk = 0; kk < 8; ++kk){
        const s16* ap = ar + kk*32 + g*8;
        s16x4 alo = *(const s16x4*)ap;
        s16x4 ahi = *(const s16x4*)(ap + 4);
        s16x8 af = __builtin_shufflevector(alo, ahi, 0,1,2,3,4,5,6,7);
        const s16* bp = br + kk*32 + g*8;
        s16x4 blo = *(const s16x4*)bp;
        s16x4 bhi = *(const s16x4*)(bp + 4);
        s16x8 bf = __builtin_shufflevector(blo, bhi, 0,1,2,3,4,5,6,7);
        acc = __builtin_amdgcn_mfma_f32_16x16x32_bf16(af, bf, acc, 0, 0, 0);
    }
    float* pd = part + (b*16 + ks)*1024;
    #pragma unroll
    for (int r = 0; r < 4; ++r){
        int i = mi*16 + g*4 + r, j = ni*16 + lm;
        pd[i*32 + j] = acc[r];
    }
}

// ---------------------------------------------------------------------------
// G2+G3) fused: attn1 softmax (rn1 from gram diag) + fold into WtT/WoT/bfo
// ---------------------------------------------------------------------------
__global__ __launch_bounds__(256) void afold_k(const float* __restrict__ part,
        const float* __restrict__ w3, const float* __restrict__ b3,
        const float* __restrict__ w4, const float* __restrict__ b4,
        float* __restrict__ WtT, float* __restrict__ WoT, float* __restrict__ bfo){
    __shared__ float rn[32];
    __shared__ float rsum[32];
    __shared__ float a1[1024];     // attn1[i][j] (exp, then normalized)
    __shared__ float w3a[1024];    // [cc][j]
    __shared__ float w3bs[1024];   // [cc][j]
    int b = blockIdx.x, t = threadIdx.x;
    if (t < 32){
        float gjj = 0.f;
        #pragma unroll 8
        for (int ps = 0; ps < 16; ++ps) gjj += part[(b*16+ps)*1024 + t*33];
        rn[t] = 1.f / fmaxf(sqrtf(gjj), 1e-12f);
    }
    for (int idx = t; idx < 1024; idx += 256){
        int i = idx >> 5, j = idx & 31;
        w3bs[idx] = w3[i*64 + 32 + j];
    }
    __syncthreads();
    for (int e = t; e < 1024; e += 256){
        int i = e >> 5, j = e & 31;
        float gij = 0.f;
        #pragma unroll 8
        for (int ps = 0; ps < 16; ++ps) gij += part[(b*16+ps)*1024 + e];
        a1[e] = __expf(rn[i]*rn[j]*gij);
    }
    __syncthreads();
    if (t < 32){
        float s = 0.f;
        #pragma unroll 8
        for (int j = 0; j < 32; ++j) s += a1[t*32 + j];
        rsum[t] = 1.f / s;
    }
    __syncthreads();
    for (int e = t; e < 1024; e += 256) a1[e] *= rsum[e >> 5];
    __syncthreads();
    for (int idx = t; idx < 1024; idx += 256){
        int cc = idx >> 5, j = idx & 31;
        float s = 0.f;
        #pragma unroll 8
        for (int i = 0; i < 32; ++i) s += w3[cc*64 + i]*a1[i*32 + j];
        w3a[idx] = s;
    }
    __syncthreads();
    int co = t;
    float w4r[32];
    #pragma unroll
    for (int cc = 0; cc < 32; ++cc) w4r[cc] = w4[co*32 + cc];
    float bfv = b4[co];
    #pragma unroll
    for (int cc = 0; cc < 32; ++cc) bfv += w4r[cc]*b3[cc];
    bfo[b*256 + co] = bfv;
    for (int j = 0; j < 32; ++j){
        float st = w4r[j];           // w4 identity term = +t residual through w4
        float so = 0.f;
        #pragma unroll 8
        for (int cc = 0; cc < 32; ++cc){
            st += w4r[cc]*w3a[cc*32 + j];
            so += w4r[cc]*w3bs[cc*32 + j];
        }
        WtT[(b*32 + j)*256 + co] = st;
        WoT[(b*32 + j)*256 + co] = so;
    }
}

// ---------------------------------------------------------------------------
// J) spatial attention via MFMA flash — 4-way j-chunk split (R14)
// ---------------------------------------------------------------------------
__global__ __launch_bounds__(256) void flashm_k(const s16* __restrict__ tTb, const float* __restrict__ rn2,
                                                float* __restrict__ partA, float* __restrict__ partL){
    __shared__ alignas(16) s16 kvb[128*36];      // [j][ci]   9216 B
    __shared__ alignas(16) s16 vts[32*132];      // [ci][j]   8448 B
    __shared__ alignas(16) s16 pls[4][16*132];   // per-wave P [m][j] 16896 B
    __shared__ float rnj[128];
    __shared__ float ri[64];
    const int ib = blockIdx.x, b = blockIdx.y, chunk = blockIdx.z;
    const int t = threadIdx.x, wv = t >> 6, lane = t & 63;
    const int lm = lane & 15, g = lane >> 4;
    const int i0 = ib*64;

    if (t < 64) ri[t] = rn2[b*4096 + i0 + t];
    s16x8 qf = *(const s16x8*)&tTb[(b*4096 + i0 + wv*16 + lm)*32 + g*8];
    __syncthreads();
    float rni4[4];
    #pragma unroll
    for (int r = 0; r < 4; ++r) rni4[r] = ri[wv*16 + g*4 + r];

    f32x4 oacc[2];
    oacc[0] = (f32x4){0.f,0.f,0.f,0.f};
    oacc[1] = (f32x4){0.f,0.f,0.f,0.f};
    float lacc[4] = {0.f,0.f,0.f,0.f};
    s16* pw = pls[wv];

    for (int jt = chunk*8; jt < chunk*8 + 8; ++jt){
        const int j0 = jt*128;
        __syncthreads();
        for (int gi = t; gi < 512; gi += 256){
            int j = gi >> 2, g8 = gi & 3;
            s16x8 v = *(const s16x8*)&tTb[(b*4096 + j0 + j)*32 + g8*8];
            s16* d = &kvb[j*36 + g8*8];
            *(s16x4*)d       = __builtin_shufflevector(v, v, 0,1,2,3);
            *(s16x4*)(d + 4) = __builtin_shufflevector(v, v, 4,5,6,7);
            #pragma unroll
            for (int e = 0; e < 8; ++e) vts[(g8*8 + e)*132 + j] = v[e];
        }
        if (t < 128) rnj[t] = rn2[b*4096 + j0 + t];
        __syncthreads();
        #pragma unroll
        for (int nt = 0; nt < 8; ++nt){
            const s16* bp = &kvb[(nt*16 + lm)*36 + g*8];
            s16x4 blo = *(const s16x4*)bp;
            s16x4 bhi = *(const s16x4*)(bp + 4);
            s16x8 bf = __builtin_shufflevector(blo, bhi, 0,1,2,3,4,5,6,7);
            f32x4 s = __builtin_amdgcn_mfma_f32_16x16x32_bf16(qf, bf,
                        (f32x4){0.f,0.f,0.f,0.f}, 0, 0, 0);
            float rj = rnj[nt*16 + lm];
            #pragma unroll
            for (int r = 0; r < 4; ++r){
                float e = __expf(s[r]*rni4[r]*rj);
                lacc[r] += e;
                pw[(g*4 + r)*132 + nt*16 + lm] = f2b(e);
            }
        }
        #pragma unroll
        for (int ks = 0; ks < 4; ++ks){
            const s16* ap = &pw[lm*132 + ks*32 + g*8];
            s16x4 alo = *(const s16x4*)ap;
            s16x4 ahi = *(const s16x4*)(ap + 4);
            s16x8 af = __builtin_shufflevector(alo, ahi, 0,1,2,3,4,5,6,7);
            #pragma unroll
            for (int n2 = 0; n2 < 2; ++n2){
                const s16* vp = &vts[(n2*16 + lm)*132 + ks*32 + g*8];
                s16x4 vlo = *(const s16x4*)vp;
                s16x4 vhi = *(const s16x4*)(vp + 4);
                s16x8 vf = __builtin_shufflevector(vlo, vhi, 0,1,2,3,4,5,6,7);
                oacc[n2] = __builtin_amdgcn_mfma_f32_16x16x32_bf16(af, vf, oacc[n2], 0, 0, 0);
            }
        }
    }
    #pragma unroll
    for (int r = 0; r < 4; ++r){
        float v = lacc[r];
        v += __shfl_xor(v, 1, 16); v += __shfl_xor(v, 2, 16);
        v += __shfl_xor(v, 4, 16); v += __shfl_xor(v, 8, 16);
        lacc[r] = v;
    }
    const int base = (b*4 + chunk)*4096 + i0 + wv*16;
    #pragma unroll
    for (int n2 = 0; n2 < 2; ++n2)
        #pragma unroll
        for (int r = 0; r < 4; ++r)
            partA[(base + g*4 + r)*32 + n2*16 + lm] = oacc[n2][r];
    if (lm == 0){
        #pragma unroll
        for (int r = 0; r < 4; ++r) partL[base + g*4 + r] = lacc[r];
    }
}

// ---------------------------------------------------------------------------
// L) fused epilogue — t from tTb, 4-chunk merge (R14)
// ---------------------------------------------------------------------------
__global__ __launch_bounds__(256) void finalfuse_k(const s16* __restrict__ tTb,
        const float* __restrict__ partA, const float* __restrict__ partL,
        const float* __restrict__ WtT, const float* __restrict__ WoT,
        const float* __restrict__ bfo, float* __restrict__ out){
    int pt = blockIdx.x, cog = blockIdx.y, b = blockIdx.z, t = threadIdx.x;
    int p = pt*256 + t;
    float l = 0.f;
    #pragma unroll
    for (int c = 0; c < 4; ++c) l += partL[(b*4 + c)*4096 + p];
    float inv = 1.f / l;
    float v3[32];
    #pragma unroll
    for (int q = 0; q < 8; ++q){
        float4 s0 = *(const float4*)&partA[((b*4 + 0)*4096 + p)*32 + q*4];
        float4 s1 = *(const float4*)&partA[((b*4 + 1)*4096 + p)*32 + q*4];
        float4 s2 = *(const float4*)&partA[((b*4 + 2)*4096 + p)*32 + q*4];
        float4 s3 = *(const float4*)&partA[((b*4 + 3)*4096 + p)*32 + q*4];
        v3[q*4+0] = (s0.x + s1.x + s2.x + s3.x)*inv;
        v3[q*4+1] = (s0.y + s1.y + s2.y + s3.y)*inv;
        v3[q*4+2] = (s0.z + s1.z + s2.z + s3.z)*inv;
        v3[q*4+3] = (s0.w + s1.w + s2.w + s3.w)*inv;
    }
    float vt[32];
    {
        const s16* tp = &tTb[(b*4096 + p)*32];
        #pragma unroll
        for (int q = 0; q < 4; ++q){
            s16x8 v = *(const s16x8*)&tp[q*8];
            #pragma unroll
            for (int e = 0; e < 8; ++e) vt[q*8 + e] = b2f_bits(v[e]);
        }
    }
    float acc[32];
    #pragma unroll
    for (int co = 0; co < 32; ++co) acc[co] = bfo[b*256 + cog*32 + co];
    for (int j = 0; j < 32; ++j){
        float vtj = vt[j];
        float vo  = v3[j];
        const float* wtr = WtT + (b*32 + j)*256 + cog*32;   // wave-uniform
        const float* wor = WoT + (b*32 + j)*256 + cog*32;   // wave-uniform
        #pragma unroll
        for (int co = 0; co < 32; ++co) acc[co] += wtr[co]*vtj + wor[co]*vo;
    }
    #pragma unroll
    for (int co = 0; co < 32; ++co)
        out[((b*256 + cog*32 + co)*4096) + p] = acc[co];
}

// ---------------------------------------------------------------------------
// Workspace layout (bytes), peak ~19.0 MB:
//   [0,        8388608)  xcl -> out1 -> gram part (256 KB) -> flash partA (8 MB)
//   [8388608, 16777216)  y0  -> tTb (1 MB at +10.5 MB)
//   [12582912, ...)      WtT/WoT/bfo (260 KB)
//   [16777216, ...)      wpk -> partL (256 KB);  rn2 near byte 18.9 MB
// ---------------------------------------------------------------------------
extern "C" void kernel_launch(void* const* d_in, const int* in_sizes, int n_in,
                              void* d_out, int out_size, void* d_ws, size_t ws_size,
                              hipStream_t stream) {
    const float* x      = (const float*)d_in[0];
    const float* w_conv = (const float*)d_in[1];
    const float* b_conv = (const float*)d_in[2];
    const float* w01 = (const float*)d_in[3];  const float* b01 = (const float*)d_in[4];
    const float* w02 = (const float*)d_in[5];  const float* b02 = (const float*)d_in[6];
    const float* w11 = (const float*)d_in[7];  const float* b11 = (const float*)d_in[8];
    const float* w12 = (const float*)d_in[9];  const float* b12 = (const float*)d_in[10];
    const float* w21 = (const float*)d_in[11]; const float* b21 = (const float*)d_in[12];
    const float* w22 = (const float*)d_in[13]; const float* b22 = (const float*)d_in[14];
    const float* w_proj = (const float*)d_in[15]; const float* b_proj = (const float*)d_in[16];
    const float* w3 = (const float*)d_in[17]; const float* b3 = (const float*)d_in[18];
    const float* w4 = (const float*)d_in[19]; const float* b4 = (const float*)d_in[20];

    char* wsb = (char*)d_ws;
    s16*   xcl  = (s16*)wsb;                        // 4,194,304 s16 (conv input)
    bf16*  out1 = (bf16*)wsb;                       // same slot, after conv
    bf16*  y0   = (bf16*)(wsb + 8388608);           // 4,194,304 bf16
    s16*   wpk  = (s16*)(wsb + 16777216);           // 589,824 s16
    float* f    = (float*)d_ws;
    float* part   = f + 0;         // gram partials 4x16x1024 f (out1 dead)
    float* partA  = f + 0;         // flash partials 4x4x4096x32 f = 8 MB
    s16*   tTb    = (s16*)(wsb + 10485760);         // 524,288 s16 = 1 MB
    float* WtT    = f + 3145728;   // byte 12,582,912  (4x32x256 f)
    float* WoT    = f + 3178496;
    float* bfo    = f + 3211264;
    float* partL  = f + 4194304;   // byte 16,777,216 (wpk dead by flashm), 64K f
    float* rn2    = f + 4726912;

    prep_k<<<dim3(832), 256, 0, stream>>>(x, xcl, w_conv, wpk);
    conv3x3m_k<<<dim3(128, 4), 256, 0, stream>>>(xcl, wpk, b_conv, y0);
    sepconv_k<<<dim3(1024), 256, 0, stream>>>(y0, w01, b01, w02, b02,
                                              w11, b11, w12, b12,
                                              w21, b21, w22, b22, out1);
    proj_k<<<dim3(64, 4), 256, 0, stream>>>(out1, w_proj, b_proj, tTb, rn2);
    gramm_k<<<dim3(16, 4), 256, 0, stream>>>(tTb, part);
    afold_k<<<dim3(4), 256, 0, stream>>>(part, w3, b3, w4, b4, WtT, WoT, bfo);
    flashm_k<<<dim3(64, 4, 4), 256, 0, stream>>>(tTb, rn2, partA, partL);
    finalfuse_k<<<dim3(16, 8, 4), 256, 0, stream>>>(tTb, partA, partL, WtT, WoT, bfo,
                                                    (float*)d_out);
}